// Round 12
// baseline (373.260 us; speedup 1.0000x reference)
//
#include <hip/hip_runtime.h>
#include <hip/hip_bf16.h>
#include <cstdint>
#include <cstddef>

typedef unsigned short u16;
typedef __bf16 bf16x8 __attribute__((ext_vector_type(8)));
typedef float f32x4 __attribute__((ext_vector_type(4)));
typedef float f32x4u __attribute__((ext_vector_type(4), aligned(4)));  // 4B-aligned vector load

#define IN_F   4096
#define OUT_F  4096
#define IC_N   409      // int(4096*0.1)
#define K_NON  3687     // 4096-409
#define K_HI0  3712     // 58*64: sigmoid boundary (BK-aligned)
#define K_LO0  4121
#define K_HI1  4530
#define K_END  4939
#define K_TOT  4992     // 78*64
#define BATCHN 8192
#define NT     78       // K-tiles of 64
#define T_SPLIT 58      // body index where state transform applies

__device__ __forceinline__ u16 f2bf(float f) {          // RNE fp32->bf16
  uint32_t u = __float_as_uint(f);
  uint32_t r = (u + 0x7FFFu + ((u >> 16) & 1u)) >> 16;
  return (u16)r;
}
__device__ __forceinline__ float bf2f(u16 h) {
  return __uint_as_float(((uint32_t)h) << 16);
}
__device__ __forceinline__ float coefj(int j) {
  return (j == 0 || j == IC_N - 1) ? 1.0f : 2.0f;
}

// ---------------- fused pack (r5-verified bodies, one dispatch):
// blocks [0, BATCHN)            -> pack A row b
// blocks [BATCHN, BATCHN+OUT_F) -> pack B row b-BATCHN
__global__ __launch_bounds__(256) void pack_ab_kernel(const float* __restrict__ x,
                                                      const float* __restrict__ Wnmda,
                                                      const float* __restrict__ Wnon,
                                                      u16* __restrict__ Ab,
                                                      u16* __restrict__ Bb) {
  __shared__ u16 hbuf[IC_N];
  __shared__ u16 lbuf[IC_N];
  const int blk = blockIdx.x;
  if (blk < BATCHN) {
    const int row = blk;
    const float* xr = x + (size_t)row * IN_F;
    for (int j = threadIdx.x; j < IC_N; j += 256) {
      const float v = xr[j] * coefj(j);
      const u16 h = f2bf(v);
      hbuf[j] = h;
      lbuf[j] = f2bf(v - bf2f(h));
    }
    __syncthreads();
    u16* outr = Ab + (size_t)row * K_TOT;
    for (int c8 = threadIdx.x; c8 < K_TOT / 8; c8 += 256) {
      const int kb = c8 * 8;
      u16 tmp[8] __attribute__((aligned(16)));
      if (kb + 8 <= K_NON) {
        const float* s = xr + IC_N + kb;
        const f32x4u v0 = *(const f32x4u*)s;
        const f32x4u v1 = *(const f32x4u*)(s + 4);
#pragma unroll
        for (int e = 0; e < 4; ++e) { tmp[e] = f2bf(v0[e]); tmp[4 + e] = f2bf(v1[e]); }
      } else if (kb < K_HI0) {
#pragma unroll
        for (int e = 0; e < 8; ++e) {
          const int k = kb + e;
          tmp[e] = (k < K_NON) ? f2bf(xr[IC_N + k]) : (u16)0;
        }
      } else {
#pragma unroll
        for (int e = 0; e < 8; ++e) {
          const int k = kb + e;
          u16 o;
          if (k < K_LO0)      o = hbuf[k - K_HI0];
          else if (k < K_HI1) o = lbuf[k - K_LO0];
          else if (k < K_END) o = hbuf[k - K_HI1];
          else                o = 0;
          tmp[e] = o;
        }
      }
      *(int4*)(outr + kb) = *(const int4*)tmp;
    }
  } else {
    const int row = blk - BATCHN;
    const float* wr = Wnon + (size_t)row * K_NON;
    const float* wc = Wnmda + (size_t)row * IC_N;
    for (int j = threadIdx.x; j < IC_N; j += 256) {
      const float v = wc[j];
      const u16 h = f2bf(v);
      hbuf[j] = h;
      lbuf[j] = f2bf(v - bf2f(h));
    }
    __syncthreads();
    u16* outr = Bb + (size_t)row * K_TOT;
    for (int c8 = threadIdx.x; c8 < K_TOT / 8; c8 += 256) {
      const int kb = c8 * 8;
      u16 tmp[8] __attribute__((aligned(16)));
      if (kb + 8 <= K_NON) {
        const float* s = wr + kb;
        const f32x4u v0 = *(const f32x4u*)s;
        const f32x4u v1 = *(const f32x4u*)(s + 4);
#pragma unroll
        for (int e = 0; e < 4; ++e) { tmp[e] = f2bf(v0[e]); tmp[4 + e] = f2bf(v1[e]); }
      } else if (kb < K_HI0) {
#pragma unroll
        for (int e = 0; e < 8; ++e) {
          const int k = kb + e;
          tmp[e] = (k < K_NON) ? f2bf(wr[k]) : (u16)0;
        }
      } else {
#pragma unroll
        for (int e = 0; e < 8; ++e) {
          const int k = kb + e;
          u16 o;
          if (k < K_LO0)      o = hbuf[k - K_HI0];
          else if (k < K_HI1) o = hbuf[k - K_LO0];
          else if (k < K_END) o = lbuf[k - K_HI1];
          else                o = 0;
          tmp[e] = o;
        }
      }
      *(int4*)(outr + kb) = *(const int4*)tmp;
    }
  }
}

// ---------------- fused GEMM: 256x256, BK=64, 8 waves; 2 barriers per body
// (one per buffer-run). Within a run (4 sub-phases, 64 MFMA) no waits —
// compiler schedules reads/MFMA freely; hazards carried by the 2 sync points.
#define GLOAD16(gp, lp)                                           \
  __builtin_amdgcn_global_load_lds(                               \
      (const __attribute__((address_space(1))) void*)(gp),        \
      (__attribute__((address_space(3))) void*)(lp), 16, 0, 0)

#define MEMFENCE() asm volatile("" ::: "memory")
#define BAR() do { MEMFENCE(); __builtin_amdgcn_s_barrier(); MEMFENCE(); } while (0)
#define VM0()   asm volatile("s_waitcnt vmcnt(0)" ::: "memory")

#define RD_AF(SET, BW, KK, MH) do {                                    \
    _Pragma("unroll")                                                  \
    for (int mm = 0; mm < 4; ++mm)                                     \
      SET[mm] = *(const bf16x8*)(LDSc + (BW) * 65536 + (KK) * 16384 +  \
                 (wRow + (MH) * 64 + mm * 16) * 64 + laneOff);         \
  } while (0)
#define RD_BF(SET, BW, KK) do {                                        \
    _Pragma("unroll")                                                  \
    for (int n = 0; n < 4; ++n)                                        \
      SET[n] = *(const bf16x8*)(LDSc + (BW) * 65536 + 32768 +          \
                (KK) * 16384 + (wCol + n * 16) * 64 + laneOff);        \
  } while (0)

#define MFMA16(AFC, BFC, MH) do {                                      \
    _Pragma("unroll")                                                  \
    for (int mm = 0; mm < 4; ++mm)                                     \
      _Pragma("unroll")                                                \
      for (int n = 0; n < 4; ++n)                                      \
        acc[(MH) * 4 + mm][n] = __builtin_amdgcn_mfma_f32_16x16x32_bf16( \
            AFC[mm], BFC[n], acc[(MH) * 4 + mm][n], 0, 0, 0);          \
  } while (0)

// One run: consume buffer BW (one K-tile, 64 MFMA); STAGE_STMT refills the
// OTHER buffer (WAR-safe: previous barrier separates its last readers).
// End: vmcnt(0) confirms the other buffer's loads (>=3 phases old), barrier.
#define RUN(BW, STAGE_STMT) do {                                       \
    STAGE_STMT;                                                        \
    __builtin_amdgcn_s_setprio(1);                                     \
    RD_BF(bfrA, BW, 0); RD_AF(afA, BW, 0, 0);                          \
    MFMA16(afA, bfrA, 0);                                              \
    RD_AF(afB, BW, 0, 1);                                              \
    MFMA16(afB, bfrA, 1);                                              \
    RD_BF(bfrB, BW, 1); RD_AF(afA, BW, 1, 0);                          \
    MFMA16(afA, bfrB, 0);                                              \
    RD_AF(afB, BW, 1, 1);                                              \
    MFMA16(afB, bfrB, 1);                                              \
    __builtin_amdgcn_s_setprio(0);                                     \
    VM0();                                                             \
    BAR();                                                             \
  } while (0)

__global__ __launch_bounds__(512, 1) void gemm_fused_kernel(
    const u16* __restrict__ Ab, const u16* __restrict__ Bb,
    const float* __restrict__ bnon, float* __restrict__ out) {
  // 8 slots of 16 KB: [buf][mat A/B][k-half]. Slot = 256 rows x 32 bf16.
  // phys = pair*128B + ((((row&1)<<2)|chunk16) ^ (pair&7))*16B  (involution)
  __shared__ __attribute__((aligned(16))) u16 LDSu[65536];
  char* LDSc = (char*)LDSu;

  const int bid = blockIdx.x;
  const int swz = ((bid & 7) << 6) | (bid >> 3);   // 512 % 8 == 0: bijective XCD swizzle
  const int bm = swz >> 4, bn = swz & 15;
  const int rowBase = bm * 256, colBase = bn * 256;

  const int tid  = threadIdx.x;
  const int w    = tid >> 6, lane = tid & 63;
  const int wm = w >> 2, wn = w & 3;               // 2 x 4 wave grid
  const int wRow = wm * 128, wCol = wn * 64;       // per-wave 128x64 output
  const int l15 = lane & 15, g = lane >> 4;

  const int laneOff = ((l15 >> 1) << 7) +
                      (((((l15 & 1) << 2) | g) ^ ((l15 >> 1) & 7)) << 4);

  int rowS[2], colS[2];
#pragma unroll
  for (int is = 0; is < 2; ++is) {
    const int d = is * 8192 + tid * 16;
    const int b = d ^ ((d >> 3) & 0x70);
    rowS[is] = ((b >> 7) << 1) | ((b >> 6) & 1);
    colS[is] = (b >> 1) & 31;
  }
  const u16* pA0 = Ab + (size_t)(rowBase + rowS[0]) * K_TOT + colS[0];
  const u16* pA1 = Ab + (size_t)(rowBase + rowS[1]) * K_TOT + colS[1];
  const u16* pB0 = Bb + (size_t)(colBase + rowS[0]) * K_TOT + colS[0];
  const u16* pB1 = Bb + (size_t)(colBase + rowS[1]) * K_TOT + colS[1];

  // bias: load, keep alive, and fully retire so the vmcnt ledger stays clean
  float bn4[4];
#pragma unroll
  for (int n = 0; n < 4; ++n) bn4[n] = bnon[colBase + wCol + n * 16 + l15];
  asm volatile("" :: "v"(bn4[0]), "v"(bn4[1]), "v"(bn4[2]), "v"(bn4[3]));
  VM0();

  // stage full buffer (A+B, both k-halves, 8 gloads) for K-tile t64
  auto stageBuf = [&](int buf, int t64) {
#pragma unroll
    for (int mat = 0; mat < 2; ++mat)
#pragma unroll
      for (int ks = 0; ks < 2; ++ks) {
        const u16* s0 = (mat ? pB0 : pA0) + t64 + ks * 32;
        const u16* s1 = (mat ? pB1 : pA1) + t64 + ks * 32;
        char* dst = LDSc + buf * 65536 + mat * 32768 + ks * 16384 + tid * 16;
        GLOAD16(s0, dst);
        GLOAD16(s1, dst + 8192);
      }
  };

  f32x4 acc[8][4] = {};
  bf16x8 afA[4], afB[4], bfrA[4], bfrB[4];

  // prologue: buf0 <- tile 0, confirmed
  stageBuf(0, 0);
  VM0();
  BAR();

  for (int T = 0; T < NT - 2; T += 2) {
    if (T == T_SPLIT) {
      // acc == x_nc @ W_non^T complete; in-place: sigmoid(acc+b) - 1
#pragma unroll
      for (int m = 0; m < 8; ++m)
#pragma unroll
        for (int n = 0; n < 4; ++n)
#pragma unroll
          for (int j = 0; j < 4; ++j) {
            const float t = acc[m][n][j] + bn4[n];
            acc[m][n][j] = 1.0f / (1.0f + __expf(-t)) - 1.0f;
          }
    }
    // run A: consume buf0 (tile T); stage buf1 <- T+1 (confirmed by run-A VM0)
    RUN(0, stageBuf(1, (T + 1) * 64));
    // run B: consume buf1 (tile T+1); stage buf0 <- T+2 (WAR-safe after BAR;
    // confirmed by run-B VM0)
    RUN(1, stageBuf(0, (T + 2) * 64));
  }

  {   // tail body: tiles NT-2 (buf0), NT-1 (buf1); run B stages nothing
    RUN(0, stageBuf(1, (NT - 1) * 64));
    RUN(1, (void)0);
  }

  // epilogue: Hill. C/D layout col=lane&15, row=(lane>>4)*4+j  [m89/m91]
#pragma unroll
  for (int m = 0; m < 8; ++m) {
#pragma unroll
    for (int n = 0; n < 4; ++n) {
#pragma unroll
      for (int j = 0; j < 4; ++j) {
        const int r = rowBase + wRow + m * 16 + g * 4 + j;
        const int c = colBase + wCol + n * 16 + l15;
        const float pre = acc[m][n][j];
        const float xn = pre * pre;
        out[(size_t)r * OUT_F + c] = xn / (0.25f + xn);
      }
    }
  }
}

// ---------------- fallback (workspace too small): naive fp32
__global__ void naive_fused_kernel(const float* __restrict__ x,
                                   const float* __restrict__ Wnmda,
                                   const float* __restrict__ Wnon,
                                   const float* __restrict__ bnon,
                                   float* __restrict__ out) {
  const long long total = (long long)BATCHN * OUT_F;
  for (long long idx = (long long)blockIdx.x * blockDim.x + threadIdx.x;
       idx < total; idx += (long long)gridDim.x * blockDim.x) {
    const int b = (int)(idx / OUT_F);
    const int o = (int)(idx % OUT_F);
    float s = bnon[o];
    for (int k = 0; k < K_NON; ++k)
      s += x[(size_t)b * IN_F + IC_N + k] * Wnon[(size_t)o * K_NON + k];
    const float state = 1.0f / (1.0f + __expf(-s)) - 1.0f;
    float ca = 0.0f;
    for (int j = 0; j < IC_N; ++j)
      ca += x[(size_t)b * IN_F + j] * coefj(j) * Wnmda[(size_t)o * IC_N + j];
    const float pre = ca + state;
    const float xn = pre * pre;
    out[idx] = xn / (0.25f + xn);
  }
}

extern "C" void kernel_launch(void* const* d_in, const int* in_sizes, int n_in,
                              void* d_out, int out_size, void* d_ws, size_t ws_size,
                              hipStream_t stream) {
  const float* x     = (const float*)d_in[0];
  const float* Wnmda = (const float*)d_in[1];
  const float* Wnon  = (const float*)d_in[2];
  const float* bnon  = (const float*)d_in[3];
  float* out = (float*)d_out;

  const size_t needA = (size_t)BATCHN * K_TOT * sizeof(u16);  // ~81.8 MB
  const size_t needB = (size_t)OUT_F * K_TOT * sizeof(u16);   // ~40.9 MB

  if (ws_size < needA + needB) {
    naive_fused_kernel<<<8192, 256, 0, stream>>>(x, Wnmda, Wnon, bnon, out);
    return;
  }

  u16* Ab = (u16*)d_ws;
  u16* Bb = Ab + (size_t)BATCHN * K_TOT;

  pack_ab_kernel<<<BATCHN + OUT_F, 256, 0, stream>>>(x, Wnmda, Wnon, Ab, Bb);
  gemm_fused_kernel<<<512, 512, 0, stream>>>(Ab, Bb, bnon, out);
}

// Round 13
// 373.001 us; speedup vs baseline: 1.0007x; 1.0007x over previous
//
#include <hip/hip_runtime.h>
#include <hip/hip_bf16.h>
#include <cstdint>
#include <cstddef>

typedef unsigned short u16;
typedef __bf16 bf16x8 __attribute__((ext_vector_type(8)));
typedef float f32x16 __attribute__((ext_vector_type(16)));
typedef float f32x4u __attribute__((ext_vector_type(4), aligned(4)));  // 4B-aligned vector load

#define IN_F   4096
#define OUT_F  4096
#define IC_N   409      // int(4096*0.1)
#define K_NON  3687     // 4096-409
#define K_HI0  3712     // 58*64: sigmoid boundary (BK-aligned)
#define K_LO0  4121
#define K_HI1  4530
#define K_END  4939
#define K_TOT  4992     // 78*64
#define BATCHN 8192
#define NT     78       // K-tiles of 64
#define T_SPLIT 58      // body index where state transform applies

__device__ __forceinline__ u16 f2bf(float f) {          // RNE fp32->bf16
  uint32_t u = __float_as_uint(f);
  uint32_t r = (u + 0x7FFFu + ((u >> 16) & 1u)) >> 16;
  return (u16)r;
}
__device__ __forceinline__ float bf2f(u16 h) {
  return __uint_as_float(((uint32_t)h) << 16);
}
__device__ __forceinline__ float coefj(int j) {
  return (j == 0 || j == IC_N - 1) ? 1.0f : 2.0f;
}

// ---------------- fused pack (r5-verified bodies, one dispatch):
// blocks [0, BATCHN)            -> pack A row b
// blocks [BATCHN, BATCHN+OUT_F) -> pack B row b-BATCHN
__global__ __launch_bounds__(256) void pack_ab_kernel(const float* __restrict__ x,
                                                      const float* __restrict__ Wnmda,
                                                      const float* __restrict__ Wnon,
                                                      u16* __restrict__ Ab,
                                                      u16* __restrict__ Bb) {
  __shared__ u16 hbuf[IC_N];
  __shared__ u16 lbuf[IC_N];
  const int blk = blockIdx.x;
  if (blk < BATCHN) {
    const int row = blk;
    const float* xr = x + (size_t)row * IN_F;
    for (int j = threadIdx.x; j < IC_N; j += 256) {
      const float v = xr[j] * coefj(j);
      const u16 h = f2bf(v);
      hbuf[j] = h;
      lbuf[j] = f2bf(v - bf2f(h));
    }
    __syncthreads();
    u16* outr = Ab + (size_t)row * K_TOT;
    for (int c8 = threadIdx.x; c8 < K_TOT / 8; c8 += 256) {
      const int kb = c8 * 8;
      u16 tmp[8] __attribute__((aligned(16)));
      if (kb + 8 <= K_NON) {
        const float* s = xr + IC_N + kb;
        const f32x4u v0 = *(const f32x4u*)s;
        const f32x4u v1 = *(const f32x4u*)(s + 4);
#pragma unroll
        for (int e = 0; e < 4; ++e) { tmp[e] = f2bf(v0[e]); tmp[4 + e] = f2bf(v1[e]); }
      } else if (kb < K_HI0) {
#pragma unroll
        for (int e = 0; e < 8; ++e) {
          const int k = kb + e;
          tmp[e] = (k < K_NON) ? f2bf(xr[IC_N + k]) : (u16)0;
        }
      } else {
#pragma unroll
        for (int e = 0; e < 8; ++e) {
          const int k = kb + e;
          u16 o;
          if (k < K_LO0)      o = hbuf[k - K_HI0];
          else if (k < K_HI1) o = lbuf[k - K_LO0];
          else if (k < K_END) o = hbuf[k - K_HI1];
          else                o = 0;
          tmp[e] = o;
        }
      }
      *(int4*)(outr + kb) = *(const int4*)tmp;
    }
  } else {
    const int row = blk - BATCHN;
    const float* wr = Wnon + (size_t)row * K_NON;
    const float* wc = Wnmda + (size_t)row * IC_N;
    for (int j = threadIdx.x; j < IC_N; j += 256) {
      const float v = wc[j];
      const u16 h = f2bf(v);
      hbuf[j] = h;
      lbuf[j] = f2bf(v - bf2f(h));
    }
    __syncthreads();
    u16* outr = Bb + (size_t)row * K_TOT;
    for (int c8 = threadIdx.x; c8 < K_TOT / 8; c8 += 256) {
      const int kb = c8 * 8;
      u16 tmp[8] __attribute__((aligned(16)));
      if (kb + 8 <= K_NON) {
        const float* s = wr + kb;
        const f32x4u v0 = *(const f32x4u*)s;
        const f32x4u v1 = *(const f32x4u*)(s + 4);
#pragma unroll
        for (int e = 0; e < 4; ++e) { tmp[e] = f2bf(v0[e]); tmp[4 + e] = f2bf(v1[e]); }
      } else if (kb < K_HI0) {
#pragma unroll
        for (int e = 0; e < 8; ++e) {
          const int k = kb + e;
          tmp[e] = (k < K_NON) ? f2bf(wr[k]) : (u16)0;
        }
      } else {
#pragma unroll
        for (int e = 0; e < 8; ++e) {
          const int k = kb + e;
          u16 o;
          if (k < K_LO0)      o = hbuf[k - K_HI0];
          else if (k < K_HI1) o = hbuf[k - K_LO0];
          else if (k < K_END) o = lbuf[k - K_HI1];
          else                o = 0;
          tmp[e] = o;
        }
      }
      *(int4*)(outr + kb) = *(const int4*)tmp;
    }
  }
}

// ---------------- fused GEMM: 256x256, BK=64, 8 waves, r11-verified pipeline
// with 32x32x16 MFMA (2382 TF rate vs 2075, half the instruction count).
// Phase = one K=16 step: 8 MFMA/wave; same slots/swizzle/stage/vmcnt ledger.
#define GLOAD16(gp, lp)                                           \
  __builtin_amdgcn_global_load_lds(                               \
      (const __attribute__((address_space(1))) void*)(gp),        \
      (__attribute__((address_space(3))) void*)(lp), 16, 0, 0)

#define MEMFENCE() asm volatile("" ::: "memory")
#define BAR() do { MEMFENCE(); __builtin_amdgcn_s_barrier(); MEMFENCE(); } while (0)
#define VM6()   asm volatile("s_waitcnt vmcnt(6)" ::: "memory")
#define VM0()   asm volatile("s_waitcnt vmcnt(0)" ::: "memory")
#define VNONE   ((void)0)

// per-lane swizzled offsets; KS&1 selects loA0/loA1 (c16 = (KS&1)*2 + khi)
#define LOSEL(KS) (((KS) & 1) ? loA1 : loA0)
// A fragments: 4 m-tiles of 32 rows; lane row = l&31, k-octet = l>>5
#define RD_A(SET, BW, KS) do {                                           \
    _Pragma("unroll")                                                    \
    for (int mm = 0; mm < 4; ++mm)                                       \
      SET[mm] = *(const bf16x8*)(LDSc + (BW) * 65536 +                   \
                 (((KS) >> 1)) * 16384 + (wRow + mm * 32) * 64 + LOSEL(KS)); \
  } while (0)
// B fragments: 2 n-tiles of 32 output-cols
#define RD_B(SET, BW, KS) do {                                           \
    _Pragma("unroll")                                                    \
    for (int nn = 0; nn < 2; ++nn)                                       \
      SET[nn] = *(const bf16x8*)(LDSc + (BW) * 65536 + 32768 +           \
                 (((KS) >> 1)) * 16384 + (wCol + nn * 32) * 64 + LOSEL(KS)); \
  } while (0)

// Phase: issue next k-step's operand reads + one slot refill; 8 MFMA on
// current operands; counted vmcnt; barrier. Ledger identical to r11.
#define PHASE(AFC, BFC, NEXT_READS, STAGE_STMT, VMSTMT) do {           \
    NEXT_READS;                                                        \
    STAGE_STMT;                                                        \
    __builtin_amdgcn_s_setprio(1);                                     \
    _Pragma("unroll")                                                  \
    for (int mm = 0; mm < 4; ++mm)                                     \
      _Pragma("unroll")                                                \
      for (int nn = 0; nn < 2; ++nn)                                   \
        acc[mm][nn] = __builtin_amdgcn_mfma_f32_32x32x16_bf16(         \
            AFC[mm], BFC[nn], acc[mm][nn], 0, 0, 0);                   \
    __builtin_amdgcn_s_setprio(0);                                     \
    VMSTMT;                                                            \
    BAR();                                                             \
  } while (0)

__global__ __launch_bounds__(512, 1) void gemm_fused_kernel(
    const u16* __restrict__ Ab, const u16* __restrict__ Bb,
    const float* __restrict__ bnon, float* __restrict__ out) {
  // 8 slots of 16 KB: [buf][mat A/B][k-half]. Slot = 256 rows x 32 bf16.
  // phys = pair*128B + ((((row&1)<<2)|chunk16) ^ (pair&7))*16B  (involution)
  __shared__ __attribute__((aligned(16))) u16 LDSu[65536];
  char* LDSc = (char*)LDSu;

  const int bid = blockIdx.x;
  const int swz = ((bid & 7) << 6) | (bid >> 3);   // 512 % 8 == 0: bijective XCD swizzle
  const int bm = swz >> 4, bn = swz & 15;
  const int rowBase = bm * 256, colBase = bn * 256;

  const int tid  = threadIdx.x;
  const int w    = tid >> 6, lane = tid & 63;
  const int wm = w >> 2, wn = w & 3;               // 2 x 4 wave grid
  const int wRow = wm * 128, wCol = wn * 64;       // per-wave 128x64 output
  const int rl = lane & 31, khi = lane >> 5;       // 32x32 operand lane mapping

  // swizzled per-lane read offsets (add to (base_row)*64; bases are mult of 32)
  const int loA0 = ((rl >> 1) << 7) +
                   (((((rl & 1) << 2) | khi) ^ ((rl >> 1) & 7)) << 4);
  const int loA1 = ((rl >> 1) << 7) +
                   (((((rl & 1) << 2) | (2 | khi)) ^ ((rl >> 1) & 7)) << 4);

  int rowS[2], colS[2];
#pragma unroll
  for (int is = 0; is < 2; ++is) {
    const int d = is * 8192 + tid * 16;
    const int b = d ^ ((d >> 3) & 0x70);
    rowS[is] = ((b >> 7) << 1) | ((b >> 6) & 1);
    colS[is] = (b >> 1) & 31;
  }
  const u16* pA0 = Ab + (size_t)(rowBase + rowS[0]) * K_TOT + colS[0];
  const u16* pA1 = Ab + (size_t)(rowBase + rowS[1]) * K_TOT + colS[1];
  const u16* pB0 = Bb + (size_t)(colBase + rowS[0]) * K_TOT + colS[0];
  const u16* pB1 = Bb + (size_t)(colBase + rowS[1]) * K_TOT + colS[1];

  // bias: per-lane columns for the two n-tiles; retire before main loop
  float bn2[2];
#pragma unroll
  for (int nn = 0; nn < 2; ++nn) bn2[nn] = bnon[colBase + wCol + nn * 32 + rl];
  asm volatile("" :: "v"(bn2[0]), "v"(bn2[1]));
  VM0();

  auto stageU = [&](int mat, int buf, int ks, int t64) {
    const u16* s0 = (mat ? pB0 : pA0) + t64 + ks * 32;
    const u16* s1 = (mat ? pB1 : pA1) + t64 + ks * 32;
    char* dst = LDSc + buf * 65536 + mat * 32768 + ks * 16384 + tid * 16;
    GLOAD16(s0, dst);
    GLOAD16(s1, dst + 8192);
  };

  f32x16 acc[4][2] = {};
  bf16x8 afA[4], afB[4], bfA[2], bfB[2];

  // prologue: tile0 full (buf0) + tile1 k0 (buf1) = 12 gloads
  stageU(0, 0, 0, 0); stageU(1, 0, 0, 0);
  stageU(0, 0, 1, 0); stageU(1, 0, 1, 0);
  stageU(0, 1, 0, 64); stageU(1, 1, 0, 64);
  asm volatile("s_waitcnt vmcnt(8)" ::: "memory"); // (0,*,k0) resident
  BAR();
  RD_A(afA, 0, 0); RD_B(bfA, 0, 0);                // p0 operands (kstep 0)

  for (int T = 0; T < NT - 2; T += 2) {
    if (T == T_SPLIT) {
      // acc == x_nc @ W_non^T complete; in-place: sigmoid(acc+b) - 1
#pragma unroll
      for (int mm = 0; mm < 4; ++mm)
#pragma unroll
        for (int nn = 0; nn < 2; ++nn)
#pragma unroll
          for (int j = 0; j < 16; ++j) {
            const float t = acc[mm][nn][j] + bn2[nn];
            acc[mm][nn][j] = 1.0f / (1.0f + __expf(-t)) - 1.0f;
          }
    }
    const int t1 = (T + 1) * 64, t2 = (T + 2) * 64, t3 = (T + 3) * 64;
    // p0..p3: buf0 (tile T, ksteps 0..3); p4..p7: buf1 (tile T+1). Reads lead 1 phase.
    PHASE(afA, bfA, { RD_A(afB, 0, 1); RD_B(bfB, 0, 1); }, stageU(0, 1, 1, t1), VM6());
    PHASE(afB, bfB, { RD_A(afA, 0, 2); RD_B(bfA, 0, 2); }, stageU(1, 1, 1, t1), VNONE);
    PHASE(afA, bfA, { RD_A(afB, 0, 3); RD_B(bfB, 0, 3); }, stageU(0, 0, 0, t2), VM6());
    PHASE(afB, bfB, { RD_A(afA, 1, 0); RD_B(bfA, 1, 0); }, stageU(1, 0, 0, t2), VNONE);
    PHASE(afA, bfA, { RD_A(afB, 1, 1); RD_B(bfB, 1, 1); }, stageU(0, 0, 1, t2), VM6());
    PHASE(afB, bfB, { RD_A(afA, 1, 2); RD_B(bfA, 1, 2); }, stageU(1, 0, 1, t2), VNONE);
    PHASE(afA, bfA, { RD_A(afB, 1, 3); RD_B(bfB, 1, 3); }, stageU(0, 1, 0, t3), VM6());
    PHASE(afB, bfB, { RD_A(afA, 0, 0); RD_B(bfA, 0, 0); }, stageU(1, 1, 0, t3), VNONE);
  }

  {   // tail body T = NT-2: stage only tile NT-1 k1; full drains
    const int t1 = (NT - 1) * 64;
    PHASE(afA, bfA, { RD_A(afB, 0, 1); RD_B(bfB, 0, 1); }, stageU(0, 1, 1, t1), VM0());
    PHASE(afB, bfB, { RD_A(afA, 0, 2); RD_B(bfA, 0, 2); }, stageU(1, 1, 1, t1), VNONE);
    PHASE(afA, bfA, { RD_A(afB, 0, 3); RD_B(bfB, 0, 3); }, VNONE,               VM0());
    PHASE(afB, bfB, { RD_A(afA, 1, 0); RD_B(bfA, 1, 0); }, VNONE,               VNONE);
    PHASE(afA, bfA, { RD_A(afB, 1, 1); RD_B(bfB, 1, 1); }, VNONE,               VM0());
    PHASE(afB, bfB, { RD_A(afA, 1, 2); RD_B(bfA, 1, 2); }, VNONE,               VNONE);
    PHASE(afA, bfA, { RD_A(afB, 1, 3); RD_B(bfB, 1, 3); }, VNONE,               VM0());
    PHASE(afB, bfB, VNONE,                                 VNONE,               VNONE);
  }

  // epilogue: Hill. 32x32 C/D layout: col=lane&31, row=(reg&3)+8*(reg>>2)+4*(lane>>5)
#pragma unroll
  for (int mm = 0; mm < 4; ++mm) {
#pragma unroll
    for (int nn = 0; nn < 2; ++nn) {
#pragma unroll
      for (int j = 0; j < 16; ++j) {
        const int r = rowBase + wRow + mm * 32 + (j & 3) + 8 * (j >> 2) + 4 * khi;
        const int c = colBase + wCol + nn * 32 + rl;
        const float pre = acc[mm][nn][j];
        const float xn = pre * pre;
        out[(size_t)r * OUT_F + c] = xn / (0.25f + xn);
      }
    }
  }
}

// ---------------- fallback (workspace too small): naive fp32
__global__ void naive_fused_kernel(const float* __restrict__ x,
                                   const float* __restrict__ Wnmda,
                                   const float* __restrict__ Wnon,
                                   const float* __restrict__ bnon,
                                   float* __restrict__ out) {
  const long long total = (long long)BATCHN * OUT_F;
  for (long long idx = (long long)blockIdx.x * blockDim.x + threadIdx.x;
       idx < total; idx += (long long)gridDim.x * blockDim.x) {
    const int b = (int)(idx / OUT_F);
    const int o = (int)(idx % OUT_F);
    float s = bnon[o];
    for (int k = 0; k < K_NON; ++k)
      s += x[(size_t)b * IN_F + IC_N + k] * Wnon[(size_t)o * K_NON + k];
    const float state = 1.0f / (1.0f + __expf(-s)) - 1.0f;
    float ca = 0.0f;
    for (int j = 0; j < IC_N; ++j)
      ca += x[(size_t)b * IN_F + j] * coefj(j) * Wnmda[(size_t)o * IC_N + j];
    const float pre = ca + state;
    const float xn = pre * pre;
    out[idx] = xn / (0.25f + xn);
  }
}

extern "C" void kernel_launch(void* const* d_in, const int* in_sizes, int n_in,
                              void* d_out, int out_size, void* d_ws, size_t ws_size,
                              hipStream_t stream) {
  const float* x     = (const float*)d_in[0];
  const float* Wnmda = (const float*)d_in[1];
  const float* Wnon  = (const float*)d_in[2];
  const float* bnon  = (const float*)d_in[3];
  float* out = (float*)d_out;

  const size_t needA = (size_t)BATCHN * K_TOT * sizeof(u16);  // ~81.8 MB
  const size_t needB = (size_t)OUT_F * K_TOT * sizeof(u16);   // ~40.9 MB

  if (ws_size < needA + needB) {
    naive_fused_kernel<<<8192, 256, 0, stream>>>(x, Wnmda, Wnon, bnon, out);
    return;
  }

  u16* Ab = (u16*)d_ws;
  u16* Bb = Ab + (size_t)BATCHN * K_TOT;

  pack_ab_kernel<<<BATCHN + OUT_F, 256, 0, stream>>>(x, Wnmda, Wnon, Ab, Bb);
  gemm_fused_kernel<<<512, 512, 0, stream>>>(Ab, Bb, bnon, out);
}

// Round 14
// 358.238 us; speedup vs baseline: 1.0419x; 1.0412x over previous
//
#include <hip/hip_runtime.h>
#include <hip/hip_bf16.h>
#include <cstdint>
#include <cstddef>

typedef unsigned short u16;
typedef __bf16 bf16x8 __attribute__((ext_vector_type(8)));
typedef float f32x4 __attribute__((ext_vector_type(4)));
typedef float f32x4u __attribute__((ext_vector_type(4), aligned(4)));  // 4B-aligned vector load

#define IN_F   4096
#define OUT_F  4096
#define IC_N   409      // int(4096*0.1)
#define K_NON  3687     // 4096-409
#define K_HI0  3712     // 58*64: sigmoid boundary (BK-aligned)
#define K_LO0  4121
#define K_HI1  4530
#define K_END  4939
#define K_TOT  4992     // 78*64
#define BATCHN 8192
#define NT     78       // K-tiles of 64
#define T_SPLIT 58      // body index where state transform applies

__device__ __forceinline__ u16 f2bf(float f) {          // RNE fp32->bf16
  uint32_t u = __float_as_uint(f);
  uint32_t r = (u + 0x7FFFu + ((u >> 16) & 1u)) >> 16;
  return (u16)r;
}
__device__ __forceinline__ float bf2f(u16 h) {
  return __uint_as_float(((uint32_t)h) << 16);
}
__device__ __forceinline__ float coefj(int j) {
  return (j == 0 || j == IC_N - 1) ? 1.0f : 2.0f;
}

// ---------------- fused pack (r5-verified bodies, one dispatch):
// blocks [0, BATCHN)            -> pack A row b
// blocks [BATCHN, BATCHN+OUT_F) -> pack B row b-BATCHN
__global__ __launch_bounds__(256) void pack_ab_kernel(const float* __restrict__ x,
                                                      const float* __restrict__ Wnmda,
                                                      const float* __restrict__ Wnon,
                                                      u16* __restrict__ Ab,
                                                      u16* __restrict__ Bb) {
  __shared__ u16 hbuf[IC_N];
  __shared__ u16 lbuf[IC_N];
  const int blk = blockIdx.x;
  if (blk < BATCHN) {
    const int row = blk;
    const float* xr = x + (size_t)row * IN_F;
    for (int j = threadIdx.x; j < IC_N; j += 256) {
      const float v = xr[j] * coefj(j);
      const u16 h = f2bf(v);
      hbuf[j] = h;
      lbuf[j] = f2bf(v - bf2f(h));
    }
    __syncthreads();
    u16* outr = Ab + (size_t)row * K_TOT;
    for (int c8 = threadIdx.x; c8 < K_TOT / 8; c8 += 256) {
      const int kb = c8 * 8;
      u16 tmp[8] __attribute__((aligned(16)));
      if (kb + 8 <= K_NON) {
        const float* s = xr + IC_N + kb;
        const f32x4u v0 = *(const f32x4u*)s;
        const f32x4u v1 = *(const f32x4u*)(s + 4);
#pragma unroll
        for (int e = 0; e < 4; ++e) { tmp[e] = f2bf(v0[e]); tmp[4 + e] = f2bf(v1[e]); }
      } else if (kb < K_HI0) {
#pragma unroll
        for (int e = 0; e < 8; ++e) {
          const int k = kb + e;
          tmp[e] = (k < K_NON) ? f2bf(xr[IC_N + k]) : (u16)0;
        }
      } else {
#pragma unroll
        for (int e = 0; e < 8; ++e) {
          const int k = kb + e;
          u16 o;
          if (k < K_LO0)      o = hbuf[k - K_HI0];
          else if (k < K_HI1) o = lbuf[k - K_LO0];
          else if (k < K_END) o = hbuf[k - K_HI1];
          else                o = 0;
          tmp[e] = o;
        }
      }
      *(int4*)(outr + kb) = *(const int4*)tmp;
    }
  } else {
    const int row = blk - BATCHN;
    const float* wr = Wnon + (size_t)row * K_NON;
    const float* wc = Wnmda + (size_t)row * IC_N;
    for (int j = threadIdx.x; j < IC_N; j += 256) {
      const float v = wc[j];
      const u16 h = f2bf(v);
      hbuf[j] = h;
      lbuf[j] = f2bf(v - bf2f(h));
    }
    __syncthreads();
    u16* outr = Bb + (size_t)row * K_TOT;
    for (int c8 = threadIdx.x; c8 < K_TOT / 8; c8 += 256) {
      const int kb = c8 * 8;
      u16 tmp[8] __attribute__((aligned(16)));
      if (kb + 8 <= K_NON) {
        const float* s = wr + kb;
        const f32x4u v0 = *(const f32x4u*)s;
        const f32x4u v1 = *(const f32x4u*)(s + 4);
#pragma unroll
        for (int e = 0; e < 4; ++e) { tmp[e] = f2bf(v0[e]); tmp[4 + e] = f2bf(v1[e]); }
      } else if (kb < K_HI0) {
#pragma unroll
        for (int e = 0; e < 8; ++e) {
          const int k = kb + e;
          tmp[e] = (k < K_NON) ? f2bf(wr[k]) : (u16)0;
        }
      } else {
#pragma unroll
        for (int e = 0; e < 8; ++e) {
          const int k = kb + e;
          u16 o;
          if (k < K_LO0)      o = hbuf[k - K_HI0];
          else if (k < K_HI1) o = hbuf[k - K_LO0];
          else if (k < K_END) o = lbuf[k - K_HI1];
          else                o = 0;
          tmp[e] = o;
        }
      }
      *(int4*)(outr + kb) = *(const int4*)tmp;
    }
  }
}

// ---------------- fused GEMM: 256x256, BK=64, 8 waves, single-barrier read-ahead
// pipeline (r9/r11-verified: gemm ~315 us, MfmaUtil ~50, conflicts 0)
#define GLOAD16(gp, lp)                                           \
  __builtin_amdgcn_global_load_lds(                               \
      (const __attribute__((address_space(1))) void*)(gp),        \
      (__attribute__((address_space(3))) void*)(lp), 16, 0, 0)

#define MEMFENCE() asm volatile("" ::: "memory")
#define BAR() do { MEMFENCE(); __builtin_amdgcn_s_barrier(); MEMFENCE(); } while (0)
#define VM6()   asm volatile("s_waitcnt vmcnt(6)" ::: "memory")
#define VM0()   asm volatile("s_waitcnt vmcnt(0)" ::: "memory")
#define VNONE   ((void)0)

#define RD_AF(SET, BW, KK, MH) do {                                    \
    _Pragma("unroll")                                                  \
    for (int mm = 0; mm < 4; ++mm)                                     \
      SET[mm] = *(const bf16x8*)(LDSc + (BW) * 65536 + (KK) * 16384 +  \
                 (wRow + (MH) * 64 + mm * 16) * 64 + laneOff);         \
  } while (0)
#define RD_BF(SET, BW, KK) do {                                        \
    _Pragma("unroll")                                                  \
    for (int n = 0; n < 4; ++n)                                        \
      SET[n] = *(const bf16x8*)(LDSc + (BW) * 65536 + 32768 +          \
                (KK) * 16384 + (wCol + n * 16) * 64 + laneOff);        \
  } while (0)

// Phase: issue next phase's operand reads + one slot refill; MFMA on current
// operands (compiler inserts fine-grained lgkmcnt for their deps); counted
// vmcnt; barrier. Hazard ledger identical to verified r4.
#define PHASE(AFC, BFC, MH, NEXT_READS, STAGE_STMT, VMSTMT) do {       \
    NEXT_READS;                                                        \
    STAGE_STMT;                                                        \
    __builtin_amdgcn_s_setprio(1);                                     \
    _Pragma("unroll")                                                  \
    for (int mm = 0; mm < 4; ++mm)                                     \
      _Pragma("unroll")                                                \
      for (int n = 0; n < 4; ++n)                                      \
        acc[(MH) * 4 + mm][n] = __builtin_amdgcn_mfma_f32_16x16x32_bf16( \
            AFC[mm], BFC[n], acc[(MH) * 4 + mm][n], 0, 0, 0);          \
    __builtin_amdgcn_s_setprio(0);                                     \
    VMSTMT;                                                            \
    BAR();                                                             \
  } while (0)

__global__ __launch_bounds__(512, 1) void gemm_fused_kernel(
    const u16* __restrict__ Ab, const u16* __restrict__ Bb,
    const float* __restrict__ bnon, float* __restrict__ out) {
  // 8 slots of 16 KB: [buf][mat A/B][k-half]. Slot = 256 rows x 32 bf16.
  // phys = pair*128B + ((((row&1)<<2)|chunk16) ^ (pair&7))*16B  (involution)
  __shared__ __attribute__((aligned(16))) u16 LDSu[65536];
  char* LDSc = (char*)LDSu;

  const int bid = blockIdx.x;
  const int swz = ((bid & 7) << 6) | (bid >> 3);   // 512 % 8 == 0: bijective XCD swizzle
  const int bm = swz >> 4, bn = swz & 15;
  const int rowBase = bm * 256, colBase = bn * 256;

  const int tid  = threadIdx.x;
  const int w    = tid >> 6, lane = tid & 63;
  const int wm = w >> 2, wn = w & 3;               // 2 x 4 wave grid
  const int wRow = wm * 128, wCol = wn * 64;       // per-wave 128x64 output
  const int l15 = lane & 15, g = lane >> 4;

  const int laneOff = ((l15 >> 1) << 7) +
                      (((((l15 & 1) << 2) | g) ^ ((l15 >> 1) & 7)) << 4);

  int rowS[2], colS[2];
#pragma unroll
  for (int is = 0; is < 2; ++is) {
    const int d = is * 8192 + tid * 16;
    const int b = d ^ ((d >> 3) & 0x70);
    rowS[is] = ((b >> 7) << 1) | ((b >> 6) & 1);
    colS[is] = (b >> 1) & 31;
  }
  const u16* pA0 = Ab + (size_t)(rowBase + rowS[0]) * K_TOT + colS[0];
  const u16* pA1 = Ab + (size_t)(rowBase + rowS[1]) * K_TOT + colS[1];
  const u16* pB0 = Bb + (size_t)(colBase + rowS[0]) * K_TOT + colS[0];
  const u16* pB1 = Bb + (size_t)(colBase + rowS[1]) * K_TOT + colS[1];

  // bias: load, keep alive, and fully retire so the vmcnt ledger stays clean
  float bn4[4];
#pragma unroll
  for (int n = 0; n < 4; ++n) bn4[n] = bnon[colBase + wCol + n * 16 + l15];
  asm volatile("" :: "v"(bn4[0]), "v"(bn4[1]), "v"(bn4[2]), "v"(bn4[3]));
  VM0();

  auto stageU = [&](int mat, int buf, int ks, int t64) {
    const u16* s0 = (mat ? pB0 : pA0) + t64 + ks * 32;
    const u16* s1 = (mat ? pB1 : pA1) + t64 + ks * 32;
    char* dst = LDSc + buf * 65536 + mat * 32768 + ks * 16384 + tid * 16;
    GLOAD16(s0, dst);
    GLOAD16(s1, dst + 8192);
  };

  f32x4 acc[8][4] = {};
  bf16x8 afA[4], afB[4], bfrA[4], bfrB[4];

  // prologue: tile0 full (buf0) + tile1 k0 (buf1) = 12 gloads
  stageU(0, 0, 0, 0); stageU(1, 0, 0, 0);
  stageU(0, 0, 1, 0); stageU(1, 0, 1, 0);
  stageU(0, 1, 0, 64); stageU(1, 1, 0, 64);
  asm volatile("s_waitcnt vmcnt(8)" ::: "memory"); // (0,*,k0) resident
  BAR();
  RD_BF(bfrA, 0, 0); RD_AF(afA, 0, 0, 0);          // p0 operands

  for (int T = 0; T < NT - 2; T += 2) {
    if (T == T_SPLIT) {
      // acc == x_nc @ W_non^T complete; in-place: sigmoid(acc+b) - 1
#pragma unroll
      for (int m = 0; m < 8; ++m)
#pragma unroll
        for (int n = 0; n < 4; ++n)
#pragma unroll
          for (int j = 0; j < 4; ++j) {
            const float t = acc[m][n][j] + bn4[n];
            acc[m][n][j] = 1.0f / (1.0f + __expf(-t)) - 1.0f;
          }
    }
    const int t1 = (T + 1) * 64, t2 = (T + 2) * 64, t3 = (T + 3) * 64;
    // p0..p3: buf0 (tile T); p4..p7: buf1 (tile T+1). Reads lead by 1 phase.
    PHASE(afA, bfrA, 0, RD_AF(afB, 0, 0, 1),                           stageU(0, 1, 1, t1), VM6());
    PHASE(afB, bfrA, 1, { RD_BF(bfrB, 0, 1); RD_AF(afA, 0, 1, 0); },   stageU(1, 1, 1, t1), VNONE);
    PHASE(afA, bfrB, 0, RD_AF(afB, 0, 1, 1),                           stageU(0, 0, 0, t2), VM6());
    PHASE(afB, bfrB, 1, { RD_BF(bfrA, 1, 0); RD_AF(afA, 1, 0, 0); },   stageU(1, 0, 0, t2), VNONE);
    PHASE(afA, bfrA, 0, RD_AF(afB, 1, 0, 1),                           stageU(0, 0, 1, t2), VM6());
    PHASE(afB, bfrA, 1, { RD_BF(bfrB, 1, 1); RD_AF(afA, 1, 1, 0); },   stageU(1, 0, 1, t2), VNONE);
    PHASE(afA, bfrB, 0, RD_AF(afB, 1, 1, 1),                           stageU(0, 1, 0, t3), VM6());
    PHASE(afB, bfrB, 1, { RD_BF(bfrA, 0, 0); RD_AF(afA, 0, 0, 0); },   stageU(1, 1, 0, t3), VNONE);
  }

  {   // tail body T = NT-2: no further buf0/next-buf1 staging; full drains
    const int t1 = (NT - 1) * 64;
    PHASE(afA, bfrA, 0, RD_AF(afB, 0, 0, 1),                           stageU(0, 1, 1, t1), VM0());
    PHASE(afB, bfrA, 1, { RD_BF(bfrB, 0, 1); RD_AF(afA, 0, 1, 0); },   stageU(1, 1, 1, t1), VNONE);
    PHASE(afA, bfrB, 0, RD_AF(afB, 0, 1, 1),                           VNONE,               VM0());
    PHASE(afB, bfrB, 1, { RD_BF(bfrA, 1, 0); RD_AF(afA, 1, 0, 0); },   VNONE,               VNONE);
    PHASE(afA, bfrA, 0, RD_AF(afB, 1, 0, 1),                           VNONE,               VM0());
    PHASE(afB, bfrA, 1, { RD_BF(bfrB, 1, 1); RD_AF(afA, 1, 1, 0); },   VNONE,               VNONE);
    PHASE(afA, bfrB, 0, RD_AF(afB, 1, 1, 1),                           VNONE,               VM0());
    PHASE(afB, bfrB, 1, VNONE,                                         VNONE,               VNONE);
  }

  // epilogue: Hill. C/D layout col=lane&15, row=(lane>>4)*4+j  [m89/m91]
#pragma unroll
  for (int m = 0; m < 8; ++m) {
#pragma unroll
    for (int n = 0; n < 4; ++n) {
#pragma unroll
      for (int j = 0; j < 4; ++j) {
        const int r = rowBase + wRow + m * 16 + g * 4 + j;
        const int c = colBase + wCol + n * 16 + l15;
        const float pre = acc[m][n][j];
        const float xn = pre * pre;
        out[(size_t)r * OUT_F + c] = xn / (0.25f + xn);
      }
    }
  }
}

// ---------------- fallback (workspace too small): naive fp32
__global__ void naive_fused_kernel(const float* __restrict__ x,
                                   const float* __restrict__ Wnmda,
                                   const float* __restrict__ Wnon,
                                   const float* __restrict__ bnon,
                                   float* __restrict__ out) {
  const long long total = (long long)BATCHN * OUT_F;
  for (long long idx = (long long)blockIdx.x * blockDim.x + threadIdx.x;
       idx < total; idx += (long long)gridDim.x * blockDim.x) {
    const int b = (int)(idx / OUT_F);
    const int o = (int)(idx % OUT_F);
    float s = bnon[o];
    for (int k = 0; k < K_NON; ++k)
      s += x[(size_t)b * IN_F + IC_N + k] * Wnon[(size_t)o * K_NON + k];
    const float state = 1.0f / (1.0f + __expf(-s)) - 1.0f;
    float ca = 0.0f;
    for (int j = 0; j < IC_N; ++j)
      ca += x[(size_t)b * IN_F + j] * coefj(j) * Wnmda[(size_t)o * IC_N + j];
    const float pre = ca + state;
    const float xn = pre * pre;
    out[idx] = xn / (0.25f + xn);
  }
}

extern "C" void kernel_launch(void* const* d_in, const int* in_sizes, int n_in,
                              void* d_out, int out_size, void* d_ws, size_t ws_size,
                              hipStream_t stream) {
  const float* x     = (const float*)d_in[0];
  const float* Wnmda = (const float*)d_in[1];
  const float* Wnon  = (const float*)d_in[2];
  const float* bnon  = (const float*)d_in[3];
  float* out = (float*)d_out;

  const size_t needA = (size_t)BATCHN * K_TOT * sizeof(u16);  // ~81.8 MB
  const size_t needB = (size_t)OUT_F * K_TOT * sizeof(u16);   // ~40.9 MB

  if (ws_size < needA + needB) {
    naive_fused_kernel<<<8192, 256, 0, stream>>>(x, Wnmda, Wnon, bnon, out);
    return;
  }

  u16* Ab = (u16*)d_ws;
  u16* Bb = Ab + (size_t)BATCHN * K_TOT;

  pack_ab_kernel<<<BATCHN + OUT_F, 256, 0, stream>>>(x, Wnmda, Wnon, Ab, Bb);
  gemm_fused_kernel<<<512, 512, 0, stream>>>(Ab, Bb, bnon, out);
}